// Round 1
// baseline (3123.626 us; speedup 1.0000x reference)
//
#include <hip/hip_runtime.h>
#include <math.h>

#define NE   2048
#define FEAT 512
#define REST 8
#define NHF  4096   // HEAD*LEN*REST per n
#define HF   512    // LEN*REST per (n,h)

// ---------------------------------------------------------------------------
// Kernel 1: y_{q,k,d}[n, hl, r] = sum_f x[n,f,r] * W[hl,f]   (unnormalized)
// plus per-n scale s = 1/sqrt(sum y^2) written to a small array (applied in K2).
// One block per n. Cooperative: octet of 8 lanes splits the 512-dim f axis,
// butterfly-reduces, lane rsub keeps element r=rsub (coalesced stores).
// ---------------------------------------------------------------------------
__global__ __launch_bounds__(256) void proj_kernel(
    const float* __restrict__ x,
    const float* __restrict__ Qw,
    const float* __restrict__ Kw,
    const float* __restrict__ Dw,
    float* __restrict__ qo, float* __restrict__ ko, float* __restrict__ dvo,
    float* __restrict__ scales)
{
    __shared__ float xs[8 * 516];   // f-slice padded (+4) to kill bank conflicts
    __shared__ float red[256];
    const int t = threadIdx.x;
    const int n = blockIdx.x;

    // stage x[n] (4096 floats): slice s = f/64 at xs[s*516 + (f%64)*8 + r]
    {
        const float4* xp = (const float4*)(x + (size_t)n * NHF);
        #pragma unroll
        for (int i = 0; i < 4; ++i) {
            int idx = t + 256 * i;
            int v0 = idx * 4;
            int slice = v0 >> 9;
            int within = v0 & 511;
            float4 v = xp[idx];
            float* dst = &xs[slice * 516 + within];
            dst[0] = v.x; dst[1] = v.y; dst[2] = v.z; dst[3] = v.w;
        }
    }
    __syncthreads();

    const int rsub = t & 7;    // f-slice ownership + final r ownership
    const int rloc = t >> 3;   // 0..31

    const float* Wb[3] = {Qw, Kw, Dw};
    float* Ob[3] = {qo, ko, dvo};
    float ssacc[3] = {0.f, 0.f, 0.f};

    for (int p = 0; p < 8; ++p) {
        const int rowA = p * 64 + rloc;
        const int rowB = rowA + 32;
        float acc[6][8];
        #pragma unroll
        for (int k = 0; k < 6; ++k)
            #pragma unroll
            for (int r = 0; r < 8; ++r) acc[k][r] = 0.f;

        const float* wr[6];
        #pragma unroll
        for (int w = 0; w < 3; ++w) {
            wr[2*w+0] = Wb[w] + (size_t)rowA * FEAT + rsub * 64;
            wr[2*w+1] = Wb[w] + (size_t)rowB * FEAT + rsub * 64;
        }
        for (int f4 = 0; f4 < 16; ++f4) {
            float xv[32];
            const float* xbase = &xs[rsub * 516 + f4 * 32];
            #pragma unroll
            for (int q4 = 0; q4 < 8; ++q4) {
                float4 v = *(const float4*)(xbase + q4 * 4);
                xv[q4*4+0] = v.x; xv[q4*4+1] = v.y;
                xv[q4*4+2] = v.z; xv[q4*4+3] = v.w;
            }
            #pragma unroll
            for (int k = 0; k < 6; ++k) {
                float4 wv = ((const float4*)wr[k])[f4];
                float wf[4] = {wv.x, wv.y, wv.z, wv.w};
                #pragma unroll
                for (int j = 0; j < 4; ++j)
                    #pragma unroll
                    for (int r = 0; r < 8; ++r)
                        acc[k][r] += wf[j] * xv[j*8+r];
            }
        }
        // octet butterfly (width 8): every lane ends with the full sums
        #pragma unroll
        for (int k = 0; k < 6; ++k) {
            #pragma unroll
            for (int r = 0; r < 8; ++r) {
                acc[k][r] += __shfl_xor(acc[k][r], 1, 8);
                acc[k][r] += __shfl_xor(acc[k][r], 2, 8);
                acc[k][r] += __shfl_xor(acc[k][r], 4, 8);
            }
            float mine = 0.f;
            #pragma unroll
            for (int r = 0; r < 8; ++r) if (r == rsub) mine = acc[k][r];
            const int w = k >> 1;
            const int row = (k & 1) ? rowB : rowA;
            ssacc[w] += mine * mine;
            // addr = n*4096 + p*512 + t  -> fully coalesced
            Ob[w][(size_t)n * NHF + row * 8 + rsub] = mine;
        }
    }
    #pragma unroll
    for (int w = 0; w < 3; ++w) {
        red[t] = ssacc[w];
        __syncthreads();
        for (int s = 128; s > 0; s >>= 1) {
            if (t < s) red[t] += red[t + s];
            __syncthreads();
        }
        if (t == 0) scales[w * NE + n] = 1.0f / sqrtf(red[0]);
        __syncthreads();
    }
}

// ---------------------------------------------------------------------------
// Kernel 2: fused scores -> exp -> combine for one head, 32-n tile.
// |score| <= 1 (unit-norm vectors) so no max-subtraction needed: accumulate
// v += exp(s)*d and l += exp(s); divide at the end.
// m-tiles of 64, f-chunks of 128 (LDS ~59KB -> 2 blocks/CU).
// ---------------------------------------------------------------------------
__global__ __launch_bounds__(256) void attn_kernel(
    const float* __restrict__ qn, const float* __restrict__ kn,
    const float* __restrict__ dn, const float* __restrict__ scales,
    float* __restrict__ out)
{
    __shared__ float q_s[32 * 132];
    __shared__ float kd_s[64 * 132];
    __shared__ float w_s[32 * 64];
    __shared__ float l_s[32];

    const int t = threadIdx.x;
    const int h = blockIdx.y;
    const int n0 = blockIdx.x * 32;
    const size_t hoff = (size_t)h * HF;

    const float* sq = scales;
    const float* sk = scales + NE;
    const float* sd = scales + 2 * NE;

    const int sn = (t >> 4) << 1;   // score rows sn, sn+1
    const int sm0 = t & 15;         // score cols sm0 + 16*i  (2-way-max LDS aliasing)
    const int fg = t & 31;          // v-phase f4 position within chunk
    const int ng = t >> 5;          // v-phase n group (4 n's)

    float vacc[4][16];
    #pragma unroll
    for (int a = 0; a < 4; ++a)
        #pragma unroll
        for (int j = 0; j < 16; ++j) vacc[a][j] = 0.f;
    float lacc0 = 0.f, lacc1 = 0.f;

    for (int mt = 0; mt < 32; ++mt) {
        const int m0 = mt * 64;
        float sc0[4] = {0.f, 0.f, 0.f, 0.f};
        float sc1[4] = {0.f, 0.f, 0.f, 0.f};
        for (int c = 0; c < 4; ++c) {
            #pragma unroll
            for (int i = 0; i < 4; ++i) {          // q chunk (scaled)
                int idx = t + 256 * i;
                int row = idx >> 5, col4 = idx & 31;
                float4 v = *(const float4*)&qn[(size_t)(n0+row)*NHF + hoff + c*128 + col4*4];
                float s = sq[n0 + row];
                float* d = &q_s[row * 132 + col4 * 4];
                d[0] = v.x*s; d[1] = v.y*s; d[2] = v.z*s; d[3] = v.w*s;
            }
            #pragma unroll
            for (int i = 0; i < 8; ++i) {          // k chunk (scaled)
                int idx = t + 256 * i;
                int row = idx >> 5, col4 = idx & 31;
                float4 v = *(const float4*)&kn[(size_t)(m0+row)*NHF + hoff + c*128 + col4*4];
                float s = sk[m0 + row];
                float* d = &kd_s[row * 132 + col4 * 4];
                d[0] = v.x*s; d[1] = v.y*s; d[2] = v.z*s; d[3] = v.w*s;
            }
            __syncthreads();
            #pragma unroll 8
            for (int f4 = 0; f4 < 32; ++f4) {
                float4 qa = *(const float4*)&q_s[sn * 132 + f4 * 4];
                float4 qb = *(const float4*)&q_s[(sn+1) * 132 + f4 * 4];
                #pragma unroll
                for (int i = 0; i < 4; ++i) {
                    float4 kv = *(const float4*)&kd_s[(sm0 + 16*i) * 132 + f4 * 4];
                    sc0[i] += qa.x*kv.x + qa.y*kv.y + qa.z*kv.z + qa.w*kv.w;
                    sc1[i] += qb.x*kv.x + qb.y*kv.y + qb.z*kv.z + qb.w*kv.w;
                }
            }
            __syncthreads();
        }
        // exp (no max needed: |s|<=1), stash weights, accumulate l
        float pl0 = 0.f, pl1 = 0.f;
        #pragma unroll
        for (int i = 0; i < 4; ++i) {
            float e0 = expf(sc0[i]);
            float e1 = expf(sc1[i]);
            w_s[sn * 64 + sm0 + 16*i] = e0;
            w_s[(sn+1) * 64 + sm0 + 16*i] = e1;
            pl0 += e0; pl1 += e1;
        }
        #pragma unroll
        for (int msk = 8; msk >= 1; msk >>= 1) {
            pl0 += __shfl_xor(pl0, msk, 16);
            pl1 += __shfl_xor(pl1, msk, 16);
        }
        lacc0 += pl0; lacc1 += pl1;
        __syncthreads();
        // combine: vacc[a][f] += w[vn][m] * d[m][f]
        for (int c = 0; c < 4; ++c) {
            #pragma unroll
            for (int i = 0; i < 8; ++i) {          // d chunk (scaled)
                int idx = t + 256 * i;
                int row = idx >> 5, col4 = idx & 31;
                float4 v = *(const float4*)&dn[(size_t)(m0+row)*NHF + hoff + c*128 + col4*4];
                float s = sd[m0 + row];
                float* d = &kd_s[row * 132 + col4 * 4];
                d[0] = v.x*s; d[1] = v.y*s; d[2] = v.z*s; d[3] = v.w*s;
            }
            __syncthreads();
            #pragma unroll 4
            for (int m4 = 0; m4 < 16; ++m4) {
                float wf[4][4];
                #pragma unroll
                for (int a = 0; a < 4; ++a) {
                    float4 wv = *(const float4*)&w_s[(ng*4+a) * 64 + m4 * 4];
                    wf[a][0] = wv.x; wf[a][1] = wv.y; wf[a][2] = wv.z; wf[a][3] = wv.w;
                }
                #pragma unroll
                for (int mm = 0; mm < 4; ++mm) {
                    float4 dv = *(const float4*)&kd_s[(m4*4+mm) * 132 + fg * 4];
                    #pragma unroll
                    for (int a = 0; a < 4; ++a) {
                        float w = wf[a][mm];
                        vacc[a][c*4+0] += w * dv.x;
                        vacc[a][c*4+1] += w * dv.y;
                        vacc[a][c*4+2] += w * dv.z;
                        vacc[a][c*4+3] += w * dv.w;
                    }
                }
            }
            __syncthreads();
        }
    }
    if ((t & 15) == 0) { l_s[sn] = lacc0; l_s[sn+1] = lacc1; }
    __syncthreads();
    #pragma unroll
    for (int a = 0; a < 4; ++a) {
        float inv = 1.0f / l_s[ng*4+a];
        size_t base = (size_t)(n0 + ng*4 + a) * NHF + hoff;
        #pragma unroll
        for (int c = 0; c < 4; ++c) {
            float4 o;
            o.x = vacc[a][c*4+0] * inv;
            o.y = vacc[a][c*4+1] * inv;
            o.z = vacc[a][c*4+2] * inv;
            o.w = vacc[a][c*4+3] * inv;
            *(float4*)&out[base + c*128 + fg*4] = o;
        }
    }
}

extern "C" void kernel_launch(void* const* d_in, const int* in_sizes, int n_in,
                              void* d_out, int out_size, void* d_ws, size_t ws_size,
                              hipStream_t stream)
{
    const float* x  = (const float*)d_in[0];
    const float* Qw = (const float*)d_in[1];
    const float* Kw = (const float*)d_in[2];
    const float* Dw = (const float*)d_in[3];

    float* ws = (float*)d_ws;
    float* qn = ws;                                   // 2048*4096 floats
    float* kn = ws + (size_t)NE * NHF;                // 2048*4096
    float* dn = ws + 2 * (size_t)NE * NHF;            // 2048*4096
    float* scales = ws + 3 * (size_t)NE * NHF;        // 3*2048

    proj_kernel<<<NE, 256, 0, stream>>>(x, Qw, Kw, Dw, qn, kn, dn, scales);
    attn_kernel<<<dim3(64, 8), 256, 0, stream>>>(qn, kn, dn, scales, (float*)d_out);
}

// Round 2
// 394.120 us; speedup vs baseline: 7.9256x; 7.9256x over previous
//
#include <hip/hip_runtime.h>
#include <math.h>

#define NE   2048
#define FEAT 512

typedef short short8 __attribute__((ext_vector_type(8)));
typedef float f32x4  __attribute__((ext_vector_type(4)));

__device__ __forceinline__ unsigned short f2bf(float f) {
    union { float f; unsigned u; } v; v.f = f;
    unsigned r = v.u + 0x7fffu + ((v.u >> 16) & 1u);   // RNE
    return (unsigned short)(r >> 16);
}
__device__ __forceinline__ float bf2f(unsigned b) {
    union { unsigned u; float f; } v; v.u = b << 16;
    return v.f;
}
__device__ __forceinline__ unsigned pack2(float a, float b) {
    return (unsigned)f2bf(a) | ((unsigned)f2bf(b) << 16);
}

// ---------------------------------------------------------------------------
// K0: x[n][f][r] fp32 -> xt[(n*8+r)][f] bf16   (f-contiguous rows for MFMA B)
// ---------------------------------------------------------------------------
__global__ __launch_bounds__(256) void xpose_kernel(const float* __restrict__ x,
                                                    unsigned short* __restrict__ xt)
{
    __shared__ float xs[8 * 516];
    const int t = threadIdx.x;
    const int n = blockIdx.x;
    const float4* xp = (const float4*)(x + (size_t)n * 4096);
    #pragma unroll
    for (int i = 0; i < 4; ++i) {
        int idx = t + 256 * i;
        float4 v = xp[idx];
        int f = idx >> 1, rh = (idx & 1) * 4;
        xs[(rh + 0) * 516 + f] = v.x;
        xs[(rh + 1) * 516 + f] = v.y;
        xs[(rh + 2) * 516 + f] = v.z;
        xs[(rh + 3) * 516 + f] = v.w;
    }
    __syncthreads();
    const int r = t >> 5, f0 = (t & 31) * 16;
    const float* src = &xs[r * 516 + f0];
    unsigned o[8];
    #pragma unroll
    for (int j = 0; j < 8; ++j) o[j] = pack2(src[2 * j], src[2 * j + 1]);
    unsigned short* dst = xt + (size_t)n * 4096 + r * 512 + f0;
    *(uint4*)dst       = make_uint4(o[0], o[1], o[2], o[3]);
    *(uint4*)(dst + 8) = make_uint4(o[4], o[5], o[6], o[7]);
}

// ---------------------------------------------------------------------------
// K1: Y[hl][(n,r)] = sum_f W[hl][f] * xt[(n,r)][f]  -> qb/kb/db [h][n][l*8+r] bf16
// 128x128 tile, K-chunks of 64, mfma_f32_16x16x32_bf16.
// ---------------------------------------------------------------------------
__global__ __launch_bounds__(256) void proj_gemm(
    const float* __restrict__ Wq, const float* __restrict__ Wk, const float* __restrict__ Wd,
    const unsigned short* __restrict__ xt,
    unsigned short* __restrict__ qb, unsigned short* __restrict__ kb, unsigned short* __restrict__ db)
{
    __shared__ unsigned short As[128 * 72];
    __shared__ unsigned short Bs[128 * 72];
    const int t = threadIdx.x;
    const int w = blockIdx.z;
    const float* W = (w == 0) ? Wq : (w == 1) ? Wk : Wd;
    unsigned short* out = (w == 0) ? qb : (w == 1) ? kb : db;
    const int M0 = blockIdx.y * 128;
    const int N0 = blockIdx.x * 128;
    const int wave = t >> 6, lane = t & 63;
    const int quad = lane >> 4, l16 = lane & 15;

    f32x4 acc[2][8];
    #pragma unroll
    for (int i = 0; i < 2; ++i)
        #pragma unroll
        for (int j = 0; j < 8; ++j) acc[i][j] = {0.f, 0.f, 0.f, 0.f};

    const int ar = t >> 2, afs = (t & 3) * 16;
    const int br = t >> 3, bcs = (t & 7) * 8;

    for (int kc = 0; kc < 8; ++kc) {
        #pragma unroll
        for (int p = 0; p < 2; ++p) {                    // A: W fp32 -> bf16
            int row = ar + p * 64;
            const float4* g = (const float4*)(W + (size_t)(M0 + row) * 512 + kc * 64 + afs);
            float4 v0 = g[0], v1 = g[1], v2 = g[2], v3 = g[3];
            unsigned short* d = &As[row * 72 + afs];
            *(uint4*)d       = make_uint4(pack2(v0.x, v0.y), pack2(v0.z, v0.w),
                                          pack2(v1.x, v1.y), pack2(v1.z, v1.w));
            *(uint4*)(d + 8) = make_uint4(pack2(v2.x, v2.y), pack2(v2.z, v2.w),
                                          pack2(v3.x, v3.y), pack2(v3.z, v3.w));
        }
        #pragma unroll
        for (int p = 0; p < 4; ++p) {                    // B: xt bf16 copy
            int row = br + p * 32;
            *(uint4*)&Bs[row * 72 + bcs] =
                *(const uint4*)(xt + (size_t)(N0 + row) * 512 + kc * 64 + bcs);
        }
        __syncthreads();
        #pragma unroll
        for (int kk = 0; kk < 2; ++kk) {
            short8 a0 = *(const short8*)&As[(wave * 32 + l16) * 72 + kk * 32 + quad * 8];
            short8 a1 = *(const short8*)&As[(wave * 32 + 16 + l16) * 72 + kk * 32 + quad * 8];
            #pragma unroll
            for (int ct = 0; ct < 8; ++ct) {
                short8 b = *(const short8*)&Bs[(ct * 16 + l16) * 72 + kk * 32 + quad * 8];
                acc[0][ct] = __builtin_amdgcn_mfma_f32_16x16x32_bf16(a0, b, acc[0][ct], 0, 0, 0);
                acc[1][ct] = __builtin_amdgcn_mfma_f32_16x16x32_bf16(a1, b, acc[1][ct], 0, 0, 0);
            }
        }
        __syncthreads();
    }
    #pragma unroll
    for (int rt = 0; rt < 2; ++rt)
        #pragma unroll
        for (int reg = 0; reg < 4; ++reg) {
            int hl = M0 + wave * 32 + rt * 16 + quad * 4 + reg;
            size_t rowbase = (size_t)(hl >> 6) * 1048576 + (size_t)(hl & 63) * 8;
            #pragma unroll
            for (int ct = 0; ct < 8; ++ct) {
                int col = N0 + ct * 16 + l16;
                out[rowbase + (size_t)(col >> 3) * 512 + (col & 7)] = f2bf(acc[rt][ct][reg]);
            }
        }
}

// ---------------------------------------------------------------------------
// K1.6: scales[w][n] = rsqrt(sum over (h,l,r) of y^2)
// ---------------------------------------------------------------------------
__global__ __launch_bounds__(256) void scales_kernel(
    const unsigned short* __restrict__ qb, const unsigned short* __restrict__ kb,
    const unsigned short* __restrict__ db, float* __restrict__ scales)
{
    __shared__ float red[256];
    const int t = threadIdx.x;
    const int n = blockIdx.x, w = blockIdx.y;
    const unsigned short* src = (w == 0) ? qb : (w == 1) ? kb : db;
    const int h = t >> 5, f0 = (t & 31) * 16;
    const unsigned short* p = src + ((size_t)h * NE + n) * 512 + f0;
    uint4 v0 = *(const uint4*)p;
    uint4 v1 = *(const uint4*)(p + 8);
    unsigned a[8] = {v0.x, v0.y, v0.z, v0.w, v1.x, v1.y, v1.z, v1.w};
    float s = 0.f;
    #pragma unroll
    for (int j = 0; j < 8; ++j) {
        float lo = bf2f(a[j] & 0xffffu), hi = bf2f(a[j] >> 16);
        s += lo * lo + hi * hi;
    }
    red[t] = s;
    __syncthreads();
    for (int st = 128; st > 0; st >>= 1) {
        if (t < st) red[t] += red[t + st];
        __syncthreads();
    }
    if (t == 0) scales[w * NE + n] = rsqrtf(red[0]);
}

// ---------------------------------------------------------------------------
// K1.5: dT[h][f][n] = db[h][n][f] * invd[n]   (64x64 tiles through LDS)
// ---------------------------------------------------------------------------
__global__ __launch_bounds__(256) void dtrans_kernel(
    const unsigned short* __restrict__ db, const float* __restrict__ invd,
    unsigned short* __restrict__ dT)
{
    __shared__ float Ts[64 * 68];
    const int t = threadIdx.x;
    const int h = blockIdx.z, n0 = blockIdx.y * 64, f0 = blockIdx.x * 64;
    const int rr = t >> 3, cs = (t & 7) * 8;
    #pragma unroll
    for (int p = 0; p < 2; ++p) {
        int row = rr + p * 32;
        float sc = invd[n0 + row];
        uint4 v = *(const uint4*)(db + ((size_t)h * NE + n0 + row) * 512 + f0 + cs);
        unsigned a[4] = {v.x, v.y, v.z, v.w};
        float* d = &Ts[row * 68 + cs];
        #pragma unroll
        for (int j = 0; j < 4; ++j) {
            d[2 * j]     = bf2f(a[j] & 0xffffu) * sc;
            d[2 * j + 1] = bf2f(a[j] >> 16) * sc;
        }
    }
    __syncthreads();
    const int f = t >> 2, ns = (t & 3) * 16;
    unsigned o[8];
    #pragma unroll
    for (int j = 0; j < 8; ++j)
        o[j] = pack2(Ts[(ns + 2 * j) * 68 + f], Ts[(ns + 2 * j + 1) * 68 + f]);
    unsigned short* dst = dT + ((size_t)h * 512 + f0 + f) * NE + n0 + ns;
    *(uint4*)dst       = make_uint4(o[0], o[1], o[2], o[3]);
    *(uint4*)(dst + 8) = make_uint4(o[4], o[5], o[6], o[7]);
}

// ---------------------------------------------------------------------------
// K2a: P[hg][n][m] = exp( (q.k) * invq[n] * invk[m] )  bf16, per 128x128 tile.
// |s|<=1 (unit vectors) so no max subtraction.
// ---------------------------------------------------------------------------
__global__ __launch_bounds__(256) void score_kernel(
    const unsigned short* __restrict__ qb, const unsigned short* __restrict__ kb,
    const float* __restrict__ scales, unsigned short* __restrict__ P, int g)
{
    __shared__ unsigned short As[128 * 72];
    __shared__ unsigned short Bs[128 * 72];
    const int t = threadIdx.x;
    const int hg = blockIdx.z, h = g * 4 + hg;
    const int n0 = blockIdx.y * 128, m0 = blockIdx.x * 128;
    const int wave = t >> 6, lane = t & 63, quad = lane >> 4, l16 = lane & 15;
    const unsigned short* qh = qb + (size_t)h * NE * 512;
    const unsigned short* kh = kb + (size_t)h * NE * 512;

    f32x4 acc[2][8];
    #pragma unroll
    for (int i = 0; i < 2; ++i)
        #pragma unroll
        for (int j = 0; j < 8; ++j) acc[i][j] = {0.f, 0.f, 0.f, 0.f};

    const int br = t >> 3, bcs = (t & 7) * 8;
    for (int kc = 0; kc < 8; ++kc) {
        #pragma unroll
        for (int p = 0; p < 4; ++p) {
            int row = br + p * 32;
            *(uint4*)&As[row * 72 + bcs] =
                *(const uint4*)(qh + (size_t)(n0 + row) * 512 + kc * 64 + bcs);
            *(uint4*)&Bs[row * 72 + bcs] =
                *(const uint4*)(kh + (size_t)(m0 + row) * 512 + kc * 64 + bcs);
        }
        __syncthreads();
        #pragma unroll
        for (int kk = 0; kk < 2; ++kk) {
            short8 a0 = *(const short8*)&As[(wave * 32 + l16) * 72 + kk * 32 + quad * 8];
            short8 a1 = *(const short8*)&As[(wave * 32 + 16 + l16) * 72 + kk * 32 + quad * 8];
            #pragma unroll
            for (int ct = 0; ct < 8; ++ct) {
                short8 b = *(const short8*)&Bs[(ct * 16 + l16) * 72 + kk * 32 + quad * 8];
                acc[0][ct] = __builtin_amdgcn_mfma_f32_16x16x32_bf16(a0, b, acc[0][ct], 0, 0, 0);
                acc[1][ct] = __builtin_amdgcn_mfma_f32_16x16x32_bf16(a1, b, acc[1][ct], 0, 0, 0);
            }
        }
        __syncthreads();
    }
    float iq[2][4], ik[8];
    #pragma unroll
    for (int rt = 0; rt < 2; ++rt)
        #pragma unroll
        for (int reg = 0; reg < 4; ++reg)
            iq[rt][reg] = scales[n0 + wave * 32 + rt * 16 + quad * 4 + reg];
    #pragma unroll
    for (int ct = 0; ct < 8; ++ct) ik[ct] = scales[NE + m0 + ct * 16 + l16];

    unsigned short* Ph = P + (size_t)hg * NE * NE;
    #pragma unroll
    for (int rt = 0; rt < 2; ++rt)
        #pragma unroll
        for (int reg = 0; reg < 4; ++reg) {
            int nl = wave * 32 + rt * 16 + quad * 4 + reg;
            unsigned short* prow = Ph + (size_t)(n0 + nl) * NE + m0;
            float qs = iq[rt][reg];
            #pragma unroll
            for (int ct = 0; ct < 8; ++ct) {
                float s = acc[rt][ct][reg] * qs * ik[ct];
                prow[ct * 16 + l16] = f2bf(__expf(s));
            }
        }
}

// ---------------------------------------------------------------------------
// K2b: V[n][f] = (sum_m P[n][m] * dT[f][m]) / (sum_m P[n][m])
// 128n x 64f tile, K=2048 in chunks of 64; l summed in fp32 during staging.
// ---------------------------------------------------------------------------
__global__ __launch_bounds__(256) void combine_kernel(
    const unsigned short* __restrict__ P, const unsigned short* __restrict__ dT,
    float* __restrict__ out, int g)
{
    __shared__ unsigned short Ps[128 * 72];
    __shared__ unsigned short Ds[64 * 72];
    __shared__ float lred[128 * 9];
    __shared__ float linv[128];
    const int t = threadIdx.x;
    const int hg = blockIdx.z, h = g * 4 + hg;
    const int n0 = blockIdx.y * 128, f0 = blockIdx.x * 64;
    const int wave = t >> 6, lane = t & 63, quad = lane >> 4, l16 = lane & 15;
    const unsigned short* Ph = P + (size_t)hg * NE * NE;
    const unsigned short* dh = dT + (size_t)h * 512 * NE;

    f32x4 acc[2][4];
    #pragma unroll
    for (int i = 0; i < 2; ++i)
        #pragma unroll
        for (int j = 0; j < 4; ++j) acc[i][j] = {0.f, 0.f, 0.f, 0.f};
    float lp[4] = {0.f, 0.f, 0.f, 0.f};

    const int br = t >> 3, bcs = (t & 7) * 8;
    for (int mc = 0; mc < 32; ++mc) {
        #pragma unroll
        for (int p = 0; p < 4; ++p) {
            int row = br + p * 32;
            uint4 v = *(const uint4*)(Ph + (size_t)(n0 + row) * NE + mc * 64 + bcs);
            *(uint4*)&Ps[row * 72 + bcs] = v;
            unsigned a[4] = {v.x, v.y, v.z, v.w};
            float s = 0.f;
            #pragma unroll
            for (int j = 0; j < 4; ++j) s += bf2f(a[j] & 0xffffu) + bf2f(a[j] >> 16);
            lp[p] += s;
        }
        #pragma unroll
        for (int p = 0; p < 2; ++p) {
            int row = br + p * 32;
            *(uint4*)&Ds[row * 72 + bcs] =
                *(const uint4*)(dh + (size_t)(f0 + row) * NE + mc * 64 + bcs);
        }
        __syncthreads();
        #pragma unroll
        for (int kk = 0; kk < 2; ++kk) {
            short8 a0 = *(const short8*)&Ps[(wave * 32 + l16) * 72 + kk * 32 + quad * 8];
            short8 a1 = *(const short8*)&Ps[(wave * 32 + 16 + l16) * 72 + kk * 32 + quad * 8];
            #pragma unroll
            for (int ct = 0; ct < 4; ++ct) {
                short8 b = *(const short8*)&Ds[(ct * 16 + l16) * 72 + kk * 32 + quad * 8];
                acc[0][ct] = __builtin_amdgcn_mfma_f32_16x16x32_bf16(a0, b, acc[0][ct], 0, 0, 0);
                acc[1][ct] = __builtin_amdgcn_mfma_f32_16x16x32_bf16(a1, b, acc[1][ct], 0, 0, 0);
            }
        }
        __syncthreads();
    }
    #pragma unroll
    for (int p = 0; p < 4; ++p) lred[(br + p * 32) * 9 + (t & 7)] = lp[p];
    __syncthreads();
    if (t < 128) {
        float s = 0.f;
        #pragma unroll
        for (int j = 0; j < 8; ++j) s += lred[t * 9 + j];
        linv[t] = 1.0f / s;
    }
    __syncthreads();
    #pragma unroll
    for (int rt = 0; rt < 2; ++rt)
        #pragma unroll
        for (int reg = 0; reg < 4; ++reg) {
            int nl = wave * 32 + rt * 16 + quad * 4 + reg;
            float li = linv[nl];
            float* orow = out + (size_t)(n0 + nl) * 4096 + h * 512 + f0;
            #pragma unroll
            for (int ct = 0; ct < 4; ++ct)
                orow[ct * 16 + l16] = acc[rt][ct][reg] * li;
        }
}

extern "C" void kernel_launch(void* const* d_in, const int* in_sizes, int n_in,
                              void* d_out, int out_size, void* d_ws, size_t ws_size,
                              hipStream_t stream)
{
    const float* x  = (const float*)d_in[0];
    const float* Qw = (const float*)d_in[1];
    const float* Kw = (const float*)d_in[2];
    const float* Dw = (const float*)d_in[3];
    float* out = (float*)d_out;

    // ws layout (84.0 MB total; P overlaps xt+db which are dead before K2a):
    char* ws = (char*)d_ws;
    unsigned short* xt = (unsigned short*)ws;                          // 16 MB
    unsigned short* db = (unsigned short*)(ws + 16777216);             // 16 MB
    unsigned short* P  = (unsigned short*)ws;                          // 32 MB (reuse)
    unsigned short* qb = (unsigned short*)(ws + 33554432);             // 16 MB
    unsigned short* kb = (unsigned short*)(ws + 33554432 + 16777216);  // 16 MB
    unsigned short* dT = (unsigned short*)(ws + 33554432 + 2 * 16777216); // 16 MB
    float* scales = (float*)(ws + 33554432 + 3 * 16777216);            // 24 KB

    xpose_kernel<<<2048, 256, 0, stream>>>(x, xt);
    proj_gemm<<<dim3(128, 4, 3), 256, 0, stream>>>(Qw, Kw, Dw, xt, qb, kb, db);
    scales_kernel<<<dim3(2048, 3), 256, 0, stream>>>(qb, kb, db, scales);
    dtrans_kernel<<<dim3(8, 32, 8), 256, 0, stream>>>(db, scales + 2 * NE, dT);
    for (int g = 0; g < 2; ++g) {
        score_kernel<<<dim3(16, 16, 4), 256, 0, stream>>>(qb, kb, scales, P, g);
        combine_kernel<<<dim3(8, 16, 4), 256, 0, stream>>>(P, dT, out, g);
    }
}